// Round 10
// baseline (495.132 us; speedup 1.0000x reference)
//
#include <hip/hip_runtime.h>
#include <math.h>

#define B_   32
#define L_   256
#define S_   64
#define D_   128
#define NTOK (B_*L_)   // 8192

// ---------------------------------------------------------------------------
// ONE fused kernel. 4 tokens/block (same b), 256 threads, 2048 blocks.
// Thread views: (wv = tid>>6, lane = tid&63) wave/token view for attn+LN;
//               (d = tid&127, pr = tid>>7) dim/token-pair view for matvecs.
// LDS regions (floats), reused across phases:
//   X  [4*132]  x tokens                (live whole kernel)
//   QK [4*528]  qk fragments -> then ctx[4*132] @0 and y[4*132] @528
//   A  [4*528]  q[4*132] -> u[4][4*132] -> o[4*132]
// 19.4 KB total -> 8 blocks/CU (32 waves/CU, the cap) for EVERY phase --
// fixes R9's 4-waves/CU starvation of the qk/epi kernels and kills 48 MB of
// intermediate HBM round-trips + 2 launches.
// ---------------------------------------------------------------------------
__global__ __launch_bounds__(256) void fused_kernel(
        const float* __restrict__ h_wq,  const float* __restrict__ h_all,
        const int* __restrict__ station_id, const float* __restrict__ adj,
        const float* __restrict__ in_proj_w, const float* __restrict__ in_proj_b,
        const float* __restrict__ out_w,  const float* __restrict__ out_b,
        const float* __restrict__ gate_w, const float* __restrict__ gate_b,
        const float* __restrict__ ln_g,   const float* __restrict__ ln_b,
        const float* __restrict__ alpha,  float* __restrict__ out) {
    __shared__ float X[4*132];
    __shared__ float QK[4*528];
    __shared__ float A[4*528];
    __shared__ float cb[4][4];
    __shared__ int   lst[64];
    __shared__ int   cnt_s;

    const int t0  = blockIdx.x * 4;   // 4 tokens, same b (4 | 256)
    const int b   = t0 >> 8;
    const int tid = threadIdx.x;
    const int wv  = tid >> 6, lane = tid & 63;
    const int d   = tid & 127, pr = tid >> 7;
    const int tA  = 2*pr, tB = 2*pr + 1;          // this thread's token pair
    const float scale = 0.17677669529663687f;     // 1/sqrt(32)

    // ---- P0: mask ballot (first 64 threads) + x staging (threads 0..127)
    if (tid < 64) {
        int sid = station_id[b];
        int s = tid;
        bool av = (adj[sid*S_ + s] > 0.0f) && (s != sid);
        unsigned long long m = __ballot(av);
        if (m == 0ull) { av = (s != sid); m = __ballot(av); }   // all-but-self
        if (m == 0ull) { av = (s == sid); m = __ballot(av); }   // S==1 safety
        int idx = __popcll(m & ((1ull << s) - 1ull));
        if (av) lst[idx] = s;
        if (s == 0) cnt_s = __popcll(m);
    }
    if (tid < 128) {
        int tok = tid >> 5, d4 = tid & 31;
        *(float4*)&X[tok*132 + d4*4] =
            *(const float4*)(h_wq + (size_t)(t0 + tok)*128 + d4*4);
    }
    __syncthreads();

    // ---- P1: q[tok][d] = qb[d] + qw[d,:].x[tok]   (2 tokens per thread)
    {
        const float4* wrow = (const float4*)(in_proj_w + (size_t)d*128);
        const float qb = in_proj_b[d];
        float a0 = qb, a1 = qb;
        const float* x0 = &X[tA*132];
        const float* x1 = &X[tB*132];
        #pragma unroll 8
        for (int j4 = 0; j4 < 32; ++j4) {
            float4 w  = wrow[j4];
            float4 u0 = *(const float4*)(x0 + j4*4);
            float4 u1 = *(const float4*)(x1 + j4*4);
            a0 += w.x*u0.x + w.y*u0.y + w.z*u0.z + w.w*u0.w;
            a1 += w.x*u1.x + w.y*u1.y + w.z*u1.z + w.w*u1.w;
        }
        A[tA*132 + d] = a0;
        A[tB*132 + d] = a1;
    }
    __syncthreads();

    // ---- P2: qk[tok][h][d] = scale * sum_j kw[h*32+j, d] * q[tok][h*32+j]
    //          (weight reads coalesced over d); cb by 16 threads.
    {
        const float* q0 = &A[tA*132];
        const float* q1 = &A[tB*132];
        #pragma unroll
        for (int h = 0; h < 4; ++h) {
            float a0 = 0.f, a1 = 0.f;
            const float* wcol = in_proj_w + (size_t)(128 + h*32)*128 + d;
            #pragma unroll 8
            for (int j = 0; j < 32; ++j) {
                float w = wcol[(size_t)j*128];   // coalesced across d-lanes
                a0 += w * q0[h*32 + j];
                a1 += w * q1[h*32 + j];
            }
            QK[tA*528 + h*132 + d] = a0 * scale;
            QK[tB*528 + h*132 + d] = a1 * scale;
        }
    }
    if (tid < 16) {
        int tok = tid >> 2, h = tid & 3;
        float s = 0.f;
        for (int j = 0; j < 32; ++j)
            s += A[tok*132 + h*32 + j] * in_proj_b[128 + h*32 + j];
        cb[tok][h] = s * scale;
    }
    __syncthreads();

    // ---- P3: single-pass online-softmax attention (wave wv owns token wv).
    // 4 groups of 16 lanes own one head each; lane owns row elems 8lg..8lg+7.
    // 2-row batched loads (MLP) + joint-max update (3 exp / 2 rows).
    {
        const int g = lane >> 4, lg = lane & 15;
        const float4 qa  = *(const float4*)&QK[wv*528 + g*132 + 8*lg];
        const float4 qb2 = *(const float4*)&QK[wv*528 + g*132 + 8*lg + 4];
        const float cbg = cb[wv][g];
        const int cnt = cnt_s;
        const float* rowbase = h_all + (size_t)(t0 + wv)*(S_*D_) + 8*lg;

        float mg = -INFINITY, ls = 0.f;
        float4 ua = {0,0,0,0}, ub = {0,0,0,0};
        int i = 0;
        for (; i + 2 <= cnt; i += 2) {
            const float* rp0 = rowbase + lst[i]*D_;
            const float* rp1 = rowbase + lst[i+1]*D_;
            float4 xa0 = *(const float4*)rp0, xb0 = *(const float4*)(rp0 + 4);
            float4 xa1 = *(const float4*)rp1, xb1 = *(const float4*)(rp1 + 4);
            float p0 = qa.x*xa0.x + qa.y*xa0.y + qa.z*xa0.z + qa.w*xa0.w
                     + qb2.x*xb0.x + qb2.y*xb0.y + qb2.z*xb0.z + qb2.w*xb0.w;
            float p1 = qa.x*xa1.x + qa.y*xa1.y + qa.z*xa1.z + qa.w*xa1.w
                     + qb2.x*xb1.x + qb2.y*xb1.y + qb2.z*xb1.z + qb2.w*xb1.w;
            p0 += __shfl_xor(p0, 8, 16);  p1 += __shfl_xor(p1, 8, 16);
            p0 += __shfl_xor(p0, 4, 16);  p1 += __shfl_xor(p1, 4, 16);
            p0 += __shfl_xor(p0, 2, 16);  p1 += __shfl_xor(p1, 2, 16);
            p0 += __shfl_xor(p0, 1, 16);  p1 += __shfl_xor(p1, 1, 16);
            float s0 = p0 + cbg, s1 = p1 + cbg;
            float n = fmaxf(mg, fmaxf(s0, s1));
            float r  = __expf(mg - n);
            float w0 = __expf(s0 - n);
            float w1 = __expf(s1 - n);
            ls = ls*r + w0 + w1;
            ua.x = ua.x*r + w0*xa0.x + w1*xa1.x;
            ua.y = ua.y*r + w0*xa0.y + w1*xa1.y;
            ua.z = ua.z*r + w0*xa0.z + w1*xa1.z;
            ua.w = ua.w*r + w0*xa0.w + w1*xa1.w;
            ub.x = ub.x*r + w0*xb0.x + w1*xb1.x;
            ub.y = ub.y*r + w0*xb0.y + w1*xb1.y;
            ub.z = ub.z*r + w0*xb0.z + w1*xb1.z;
            ub.w = ub.w*r + w0*xb0.w + w1*xb1.w;
            mg = n;
        }
        if (i < cnt) {   // odd tail
            const float* rp0 = rowbase + lst[i]*D_;
            float4 xa0 = *(const float4*)rp0, xb0 = *(const float4*)(rp0 + 4);
            float p0 = qa.x*xa0.x + qa.y*xa0.y + qa.z*xa0.z + qa.w*xa0.w
                     + qb2.x*xb0.x + qb2.y*xb0.y + qb2.z*xb0.z + qb2.w*xb0.w;
            p0 += __shfl_xor(p0, 8, 16);
            p0 += __shfl_xor(p0, 4, 16);
            p0 += __shfl_xor(p0, 2, 16);
            p0 += __shfl_xor(p0, 1, 16);
            float s0 = p0 + cbg;
            float n = fmaxf(mg, s0);
            float r = __expf(mg - n), w0 = __expf(s0 - n);
            ls = ls*r + w0;
            ua.x = ua.x*r + w0*xa0.x; ua.y = ua.y*r + w0*xa0.y;
            ua.z = ua.z*r + w0*xa0.z; ua.w = ua.w*r + w0*xa0.w;
            ub.x = ub.x*r + w0*xb0.x; ub.y = ub.y*r + w0*xb0.y;
            ub.z = ub.z*r + w0*xb0.z; ub.w = ub.w*r + w0*xb0.w;
        }
        float inv = 1.f / ls;
        ua.x *= inv; ua.y *= inv; ua.z *= inv; ua.w *= inv;
        ub.x *= inv; ub.y *= inv; ub.z *= inv; ub.w *= inv;
    __syncthreads();   // A's q is dead everywhere; safe to overwrite with u
        *(float4*)&A[wv*528 + g*132 + 8*lg]     = ua;
        *(float4*)&A[wv*528 + g*132 + 8*lg + 4] = ub;
    }
    __syncthreads();

    // ---- P4: ctx[tok][d] = vb[d] + vw[d,:].u[tok][h(d)]   -> QK[tok*132+d]
    {
        const int h = d >> 5;
        const float4* vwrow = (const float4*)(in_proj_w + (size_t)(256 + d)*128);
        const float vb = in_proj_b[256 + d];
        float a0 = vb, a1 = vb;
        const float* u0 = &A[tA*528 + h*132];
        const float* u1 = &A[tB*528 + h*132];
        #pragma unroll 8
        for (int j4 = 0; j4 < 32; ++j4) {
            float4 w  = vwrow[j4];
            float4 v0 = *(const float4*)(u0 + j4*4);
            float4 v1 = *(const float4*)(u1 + j4*4);
            a0 += w.x*v0.x + w.y*v0.y + w.z*v0.z + w.w*v0.w;
            a1 += w.x*v1.x + w.y*v1.y + w.z*v1.z + w.w*v1.w;
        }
        __syncthreads();   // all qk reads done; QK reusable
        QK[tA*132 + d] = a0;
        QK[tB*132 + d] = a1;
    }
    __syncthreads();

    // ---- P5: o[tok][d] = ob[d] + ow[d,:].ctx[tok]  -> A[tok*132+d]
    {
        const float4* wrow = (const float4*)(out_w + (size_t)d*128);
        const float ob = out_b[d];
        float a0 = ob, a1 = ob;
        const float* c0 = &QK[tA*132];
        const float* c1 = &QK[tB*132];
        #pragma unroll 8
        for (int j4 = 0; j4 < 32; ++j4) {
            float4 w  = wrow[j4];
            float4 v0 = *(const float4*)(c0 + j4*4);
            float4 v1 = *(const float4*)(c1 + j4*4);
            a0 += w.x*v0.x + w.y*v0.y + w.z*v0.z + w.w*v0.w;
            a1 += w.x*v1.x + w.y*v1.y + w.z*v1.z + w.w*v1.w;
        }
        __syncthreads();   // all u reads done; A reusable
        A[tA*132 + d] = a0;
        A[tB*132 + d] = a1;
    }
    __syncthreads();

    // ---- P6: gate + residual -> y into QK[528 + tok*132 + d]
    {
        const float4* wrow = (const float4*)(gate_w + (size_t)d*256);
        const float gb = gate_b[d];
        float g0 = gb, g1 = gb;
        const float* x0 = &X[tA*132];
        const float* x1 = &X[tB*132];
        const float* o0 = &A[tA*132];
        const float* o1 = &A[tB*132];
        #pragma unroll 4
        for (int j4 = 0; j4 < 32; ++j4) {
            float4 wx = wrow[j4];
            float4 wo = wrow[32 + j4];
            float4 vx0 = *(const float4*)(x0 + j4*4);
            float4 vx1 = *(const float4*)(x1 + j4*4);
            float4 vo0 = *(const float4*)(o0 + j4*4);
            float4 vo1 = *(const float4*)(o1 + j4*4);
            g0 += wx.x*vx0.x + wx.y*vx0.y + wx.z*vx0.z + wx.w*vx0.w
                + wo.x*vo0.x + wo.y*vo0.y + wo.z*vo0.z + wo.w*vo0.w;
            g1 += wx.x*vx1.x + wx.y*vx1.y + wx.z*vx1.z + wx.w*vx1.w
                + wo.x*vo1.x + wo.y*vo1.y + wo.z*vo1.z + wo.w*vo1.w;
        }
        const float al = alpha[0];
        float s0 = 1.0f / (1.0f + __expf(-g0));
        float s1 = 1.0f / (1.0f + __expf(-g1));
        QK[528 + tA*132 + d] = x0[d] + al * s0 * o0[d];
        QK[528 + tB*132 + d] = x1[d] + al * s1 * o1[d];
    }
    __syncthreads();

    // ---- P7: LayerNorm, wave wv owns token wv (dims lane, lane+64)
    {
        float y0 = QK[528 + wv*132 + lane];
        float y1 = QK[528 + wv*132 + 64 + lane];
        float s = y0 + y1;
        #pragma unroll
        for (int o = 32; o >= 1; o >>= 1) s += __shfl_xor(s, o);
        float mu = s * (1.0f/128.0f);
        float d0 = y0 - mu, d1 = y1 - mu;
        float v = d0*d0 + d1*d1;
        #pragma unroll
        for (int o = 32; o >= 1; o >>= 1) v += __shfl_xor(v, o);
        float rs = rsqrtf(v*(1.0f/128.0f) + 1e-5f);
        out[(size_t)(t0 + wv)*128 + lane]      = d0*rs*ln_g[lane]    + ln_b[lane];
        out[(size_t)(t0 + wv)*128 + 64 + lane] = d1*rs*ln_g[64+lane] + ln_b[64+lane];
    }
}

// ---------------------------------------------------------------------------
extern "C" void kernel_launch(void* const* d_in, const int* in_sizes, int n_in,
                              void* d_out, int out_size, void* d_ws, size_t ws_size,
                              hipStream_t stream) {
    const float* h_wq       = (const float*)d_in[0];
    const float* h_all      = (const float*)d_in[1];
    const int*   station_id = (const int*)  d_in[2];
    const float* adj        = (const float*)d_in[3];
    const float* in_proj_w  = (const float*)d_in[4];
    const float* in_proj_b  = (const float*)d_in[5];
    const float* out_w      = (const float*)d_in[6];
    const float* out_b      = (const float*)d_in[7];
    const float* gate_w     = (const float*)d_in[8];
    const float* gate_b     = (const float*)d_in[9];
    const float* ln_g       = (const float*)d_in[10];
    const float* ln_b       = (const float*)d_in[11];
    const float* alpha      = (const float*)d_in[12];
    float* out = (float*)d_out;

    fused_kernel<<<NTOK/4, 256, 0, stream>>>(
        h_wq, h_all, station_id, adj, in_proj_w, in_proj_b,
        out_w, out_b, gate_w, gate_b, ln_g, ln_b, alpha, out);
}